// Round 1
// baseline (224.562 us; speedup 1.0000x reference)
//
#include <hip/hip_runtime.h>
#include <hip/hip_bf16.h>
#include <math.h>

#pragma clang fp contract(off)

#define BSZ   16
#define NMAXG 64
#define NAA   8400
#define NCC   80
#define KTOP  13

// ---- reference-faithful CIoU, clipped at 0 (gt = box1, pd = box2) ----
__device__ __forceinline__ float ciou_clip(float gx1, float gy1, float gx2, float gy2,
                                           float px1, float py1, float px2, float py2) {
    const float E = 1e-7f;
    float w1 = gx2 - gx1, h1 = gy2 - gy1 + E;
    float w2 = px2 - px1, h2 = py2 - py1 + E;
    float iw = fminf(gx2, px2) - fmaxf(gx1, px1); iw = fmaxf(iw, 0.0f);
    float ih = fminf(gy2, py2) - fmaxf(gy1, py1); ih = fmaxf(ih, 0.0f);
    float inter = iw * ih;
    float uni = w1 * h1 + w2 * h2 - inter + E;
    float iou = inter / uni;
    float cw = fmaxf(gx2, px2) - fminf(gx1, px1);
    float ch = fmaxf(gy2, py2) - fminf(gy1, py1);
    float c2 = cw * cw + ch * ch + E;
    float dx = px1 + px2 - gx1 - gx2;
    float dy = py1 + py2 - gy1 - gy2;
    float rho2 = (dx * dx + dy * dy) / 4.0f;
    float da = atanf(w2 / h2) - atanf(w1 / h1);
    float v = 0.4052847345693511f * (da * da);   // 4/pi^2
    float alpha = v / (v - iou + (1.0f + E));
    float r = iou - (rho2 / c2 + v * alpha);
    return fmaxf(r, 0.0f);
}

// raw (un-normalized) cost components: shape, area, wh-ratio
__device__ __forceinline__ void cost_raw(float w1, float h1, float w2, float h2,
                                         float& cs, float& ca, float& cwr) {
    float gt_r = fminf(w1, h1) / fmaxf(w1, h1);
    float pd_r = fminf(w2, h2) / fmaxf(w2, h2);
    cs = 1.0f - fabsf(gt_r - pd_r) / fmaxf(gt_r, pd_r);
    float ga = w1 * h1, pa = w2 * h2;
    ca = 1.0f - fabsf(ga - pa) / fmaxf(ga, pa);
    float r1 = w1 / h1, r2 = w2 / h2;
    cwr = fminf(r1, r2) / fmaxf(r1, r2);
}

// ---- K1: one block per (b, n) gt-row: cost maxes, metric, top-13, fg/firstn atomics ----
__global__ __launch_bounds__(256) void k_rows(
    const float* __restrict__ pd_scores, const float* __restrict__ pd_bboxes,
    const float* __restrict__ anc, const int* __restrict__ gt_labels,
    const float* __restrict__ gt_bboxes, const float* __restrict__ mask_gt,
    unsigned int* __restrict__ fg, unsigned int* __restrict__ firstn,
    float* __restrict__ rowmax)
{
    __shared__ float met[NAA];
    __shared__ float red[3][4];
    __shared__ unsigned long long bred[4];

    int row = blockIdx.x;            // b*NMAXG + n
    int b = row >> 6, n = row & 63;
    int t = threadIdx.x;
    int wave = t >> 6, lane = t & 63;

    float gx1 = gt_bboxes[row * 4 + 0], gy1 = gt_bboxes[row * 4 + 1];
    float gx2 = gt_bboxes[row * 4 + 2], gy2 = gt_bboxes[row * 4 + 3];
    float w1 = gx2 - gx1, h1 = gy2 - gy1 + 1e-7f;
    const float4* pb = (const float4*)(pd_bboxes + (size_t)b * NAA * 4);

    // phase A: row maxes of the 3 cost components
    float ms = -1e30f, ma = -1e30f, mw = -1e30f;
    for (int a = t; a < NAA; a += 256) {
        float4 p = pb[a];
        float w2 = p.z - p.x, h2 = p.w - p.y + 1e-7f;
        float cs, ca, cwr;
        cost_raw(w1, h1, w2, h2, cs, ca, cwr);
        ms = fmaxf(ms, cs); ma = fmaxf(ma, ca); mw = fmaxf(mw, cwr);
    }
    for (int o = 32; o; o >>= 1) {
        ms = fmaxf(ms, __shfl_xor(ms, o));
        ma = fmaxf(ma, __shfl_xor(ma, o));
        mw = fmaxf(mw, __shfl_xor(mw, o));
    }
    if (lane == 0) { red[0][wave] = ms; red[1][wave] = ma; red[2][wave] = mw; }
    __syncthreads();
    ms = fmaxf(fmaxf(red[0][0], red[0][1]), fmaxf(red[0][2], red[0][3]));
    ma = fmaxf(fmaxf(red[1][0], red[1][1]), fmaxf(red[1][2], red[1][3]));
    mw = fmaxf(fmaxf(red[2][0], red[2][1]), fmaxf(red[2][2], red[2][3]));
    if (t == 0) { rowmax[row * 3 + 0] = ms; rowmax[row * 3 + 1] = ma; rowmax[row * 3 + 2] = mw; }
    float dms = ms + 1e-7f, dma = ma + 1e-7f, dmw = mw + 1e-7f;

    // phase B: align_metric * mask_in_gts into LDS
    int lbl = gt_labels[row];
    const float* sc = pd_scores + (size_t)b * NAA * NCC + lbl;
    const float2* ap2 = (const float2*)anc;
    for (int a = t; a < NAA; a += 256) {
        float4 p = pb[a];
        float w2 = p.z - p.x, h2 = p.w - p.y + 1e-7f;
        float cs, ca, cwr;
        cost_raw(w1, h1, w2, h2, cs, ca, cwr);
        float cost = ((cs / dms + cwr / dmw) + ca / dma) / 3.0f;  // (ns + nr + na)/3
        cost = fmaxf(cost, 0.0f);
        float ov = ciou_clip(gx1, gy1, gx2, gy2, p.x, p.y, p.z, p.w);
        float s = sc[(size_t)a * NCC];
        float o2 = ov * ov; float o3 = o2 * ov; float ov6 = o3 * o3;
        float align = (s * ov6) * cost;
        float2 apv = ap2[a];
        float d = fminf(fminf(apv.x - gx1, apv.y - gy1), fminf(gx2 - apv.x, gy2 - apv.y));
        met[a] = (d > 1e-9f) ? align : 0.0f;
    }
    __syncthreads();

    if (mask_gt[row] <= 0.0f) return;   // block-uniform exit: no selections for this row

    // phase C: top-13 (value desc, index asc — matches lax.top_k tie-break)
    for (int k = 0; k < KTOP; k++) {
        unsigned long long best = 0ull;
        for (int a = t; a < NAA; a += 256) {
            float v = met[a];
            if (v >= 0.0f) {   // removed entries are -1
                unsigned long long key =
                    ((unsigned long long)__float_as_uint(v) << 32)
                    | (unsigned long long)(0xFFFFFFFFu - (unsigned)a);
                best = (key > best) ? key : best;
            }
        }
        for (int o = 32; o; o >>= 1) {
            unsigned long long ot = __shfl_xor(best, o);
            best = (ot > best) ? ot : best;
        }
        if (lane == 0) bred[wave] = best;
        __syncthreads();
        unsigned long long b0 = bred[0], b1 = bred[1], b2 = bred[2], b3 = bred[3];
        unsigned long long m01 = b0 > b1 ? b0 : b1;
        unsigned long long m23 = b2 > b3 ? b2 : b3;
        best = m01 > m23 ? m01 : m23;
        int aidx = (int)(0xFFFFFFFFu - (unsigned)(best & 0xFFFFFFFFull));
        if (t == 0) {
            met[aidx] = -1.0f;
            float2 apv = ap2[aidx];
            float d = fminf(fminf(apv.x - gx1, apv.y - gy1), fminf(gx2 - apv.x, gy2 - apv.y));
            if (d > 1e-9f) {           // mask_pos = mask_topk * mask_in_gts
                atomicAdd(&fg[b * NAA + aidx], 1u);
                atomicMin(&firstn[b * NAA + aidx], (unsigned)n);
            }
        }
        __syncthreads();
    }
}

// ---- K2: per anchor: resolve multi-claim via overlap argmax, recompute align, row maxes ----
__global__ __launch_bounds__(256) void k_resolve(
    const float* __restrict__ pd_scores, const float* __restrict__ pd_bboxes,
    const int* __restrict__ gt_labels, const float* __restrict__ gt_bboxes,
    const unsigned int* __restrict__ fg, const unsigned int* __restrict__ firstn,
    const float* __restrict__ rowmax,
    int* __restrict__ finaln, float* __restrict__ finalalign,
    unsigned int* __restrict__ pos_align, unsigned int* __restrict__ pos_ov)
{
    int i = blockIdx.x * 256 + threadIdx.x;   // b*NAA + a
    if (i >= BSZ * NAA) return;
    int b = i / NAA;
    unsigned int c = fg[i];
    if (c == 0u) { finaln[i] = -1; finalalign[i] = 0.0f; return; }

    const float4 p = ((const float4*)pd_bboxes)[i];
    int nstar; float ovstar;
    if (c == 1u) {
        nstar = (int)firstn[i];
        const float4 g = ((const float4*)gt_bboxes)[b * NMAXG + nstar];
        ovstar = ciou_clip(g.x, g.y, g.z, g.w, p.x, p.y, p.z, p.w);
    } else {
        // is_max: argmax over ALL n of clipped ciou, first max wins
        float bestv = -1.0f; nstar = 0; ovstar = 0.0f;
        for (int nn = 0; nn < NMAXG; nn++) {
            const float4 g = ((const float4*)gt_bboxes)[b * NMAXG + nn];
            float ov = ciou_clip(g.x, g.y, g.z, g.w, p.x, p.y, p.z, p.w);
            if (ov > bestv) { bestv = ov; nstar = nn; ovstar = ov; }
        }
    }
    const float4 g = ((const float4*)gt_bboxes)[b * NMAXG + nstar];
    float w1 = g.z - g.x, h1 = g.w - g.y + 1e-7f;
    float w2 = p.z - p.x, h2 = p.w - p.y + 1e-7f;
    float cs, ca, cwr;
    cost_raw(w1, h1, w2, h2, cs, ca, cwr);
    const float* rm = rowmax + (b * NMAXG + nstar) * 3;
    float cost = ((cs / (rm[0] + 1e-7f) + cwr / (rm[2] + 1e-7f)) + ca / (rm[1] + 1e-7f)) / 3.0f;
    cost = fmaxf(cost, 0.0f);
    int lbl = gt_labels[b * NMAXG + nstar];
    float s = pd_scores[(size_t)i * NCC + lbl];
    float o2 = ovstar * ovstar, o3 = o2 * ovstar, ov6 = o3 * o3;
    float align = (s * ov6) * cost;
    finaln[i] = nstar;
    finalalign[i] = align;
    // all values >= 0 -> float bits order as uint
    atomicMax(&pos_align[b * NMAXG + nstar], __float_as_uint(align));
    atomicMax(&pos_ov[b * NMAXG + nstar], __float_as_uint(ovstar));
}

// ---- K3: write outputs (labels, bboxes, score scatter, fg_mask) ----
__global__ __launch_bounds__(256) void k_out(
    const int* __restrict__ gt_labels, const float* __restrict__ gt_bboxes,
    const int* __restrict__ finaln, const float* __restrict__ finalalign,
    const unsigned int* __restrict__ pos_align, const unsigned int* __restrict__ pos_ov,
    float* __restrict__ out)
{
    int i = blockIdx.x * 256 + threadIdx.x;   // b*NAA + a
    if (i >= BSZ * NAA) return;
    int b = i / NAA;
    int nf = finaln[i];
    int tgt = (nf >= 0) ? nf : 0;            // argmax of all-zero mask column = 0
    int lbl = gt_labels[b * NMAXG + tgt];
    float4 g = ((const float4*)gt_bboxes)[b * NMAXG + tgt];

    out[i] = (float)lbl;                                          // target_labels
    ((float4*)(out + (size_t)BSZ * NAA))[i] = g;                  // target_bboxes
    float* ofg = out + (size_t)BSZ * NAA * (5 + NCC);             // fg_mask
    if (nf >= 0) {
        float pa = __uint_as_float(pos_align[b * NMAXG + nf]);
        float po = __uint_as_float(pos_ov[b * NMAXG + nf]);
        float norm = (finalalign[i] * po) / (pa + 1e-9f);
        out[(size_t)BSZ * NAA * 5 + (size_t)i * NCC + lbl] = norm; // target_scores
        ofg[i] = 1.0f;
    } else {
        ofg[i] = 0.0f;
    }
}

extern "C" void kernel_launch(void* const* d_in, const int* in_sizes, int n_in,
                              void* d_out, int out_size, void* d_ws, size_t ws_size,
                              hipStream_t stream)
{
    const float* pd_scores = (const float*)d_in[0];
    const float* pd_bboxes = (const float*)d_in[1];
    const float* anc       = (const float*)d_in[2];
    const int*   gt_labels = (const int*)d_in[3];
    const float* gt_bboxes = (const float*)d_in[4];
    const float* mask_gt   = (const float*)d_in[5];
    float* out = (float*)d_out;

    char* ws = (char*)d_ws;
    const size_t NBA = (size_t)BSZ * NAA * 4;   // 537600 bytes per per-anchor u32/f32 array
    unsigned int* fg       = (unsigned int*)(ws);
    unsigned int* firstn   = (unsigned int*)(ws + NBA);
    int*          finaln   = (int*)(ws + 2 * NBA);
    float*        fnalign  = (float*)(ws + 3 * NBA);
    unsigned int* posal    = (unsigned int*)(ws + 4 * NBA);            // 4096 B
    unsigned int* posov    = (unsigned int*)(ws + 4 * NBA + 4096);     // 4096 B
    float*        rowmax   = (float*)(ws + 4 * NBA + 8192);            // 12288 B

    // per-call re-init (harness does not re-poison between replays)
    hipMemsetAsync(fg, 0, NBA, stream);
    hipMemsetAsync(firstn, 0xFF, NBA, stream);                 // +inf for atomicMin
    hipMemsetAsync(posal, 0, 8192, stream);                    // covers posov too
    hipMemsetAsync(out + (size_t)BSZ * NAA * 5, 0,
                   (size_t)BSZ * NAA * NCC * sizeof(float), stream);   // scores region

    k_rows<<<BSZ * NMAXG, 256, 0, stream>>>(pd_scores, pd_bboxes, anc, gt_labels,
                                            gt_bboxes, mask_gt, fg, firstn, rowmax);
    int grid = (BSZ * NAA + 255) / 256;
    k_resolve<<<grid, 256, 0, stream>>>(pd_scores, pd_bboxes, gt_labels, gt_bboxes,
                                        fg, firstn, rowmax, finaln, fnalign, posal, posov);
    k_out<<<grid, 256, 0, stream>>>(gt_labels, gt_bboxes, finaln, fnalign, posal, posov, out);
}

// Round 2
// 123.189 us; speedup vs baseline: 1.8229x; 1.8229x over previous
//
#include <hip/hip_runtime.h>
#include <hip/hip_bf16.h>
#include <math.h>

#pragma clang fp contract(off)

#define BSZ   16
#define NMAXG 64
#define NAA   8400
#define NCC   80
#define KTOP  13
#define CAP   768

// CIoU (clipped at 0) with precomputed ga = w1*h1, pa = w2*h2, da = atan(w2/h2)-atan(w1/h1)
__device__ __forceinline__ float ciou_pre(float gx1, float gy1, float gx2, float gy2,
                                          float px1, float py1, float px2, float py2,
                                          float ga, float pa, float da) {
    const float E = 1e-7f;
    float iw = fminf(gx2, px2) - fmaxf(gx1, px1); iw = fmaxf(iw, 0.0f);
    float ih = fminf(gy2, py2) - fmaxf(gy1, py1); ih = fmaxf(ih, 0.0f);
    float inter = iw * ih;
    float uni = ga + pa - inter + E;
    float iou = inter / uni;
    float cw = fmaxf(gx2, px2) - fminf(gx1, px1);
    float ch = fmaxf(gy2, py2) - fminf(gy1, py1);
    float c2 = cw * cw + ch * ch + E;
    float dx = px1 + px2 - gx1 - gx2;
    float dy = py1 + py2 - gy1 - gy2;
    float rho2 = (dx * dx + dy * dy) / 4.0f;
    float v = 0.4052847345693511f * (da * da);   // 4/pi^2
    float alpha = v / (v - iou + (1.0f + E));
    float r = iou - (rho2 / c2 + v * alpha);
    return fmaxf(r, 0.0f);
}

// ---- K0: per-anchor precompute {pd_r, area, r2, atan(r2)}; per-row {gt_r, area, r1, atan(r1)} ----
__global__ __launch_bounds__(256) void k_pre(
    const float* __restrict__ pd_bboxes, const float* __restrict__ gt_bboxes,
    float4* __restrict__ precomp, float4* __restrict__ rowpre)
{
    int i = blockIdx.x * 256 + threadIdx.x;
    if (i < BSZ * NAA) {
        float4 p = ((const float4*)pd_bboxes)[i];
        float w2 = p.z - p.x, h2 = p.w - p.y + 1e-7f;
        float r2 = w2 / h2;
        float4 q;
        q.x = fminf(w2, h2) / fmaxf(w2, h2);   // pd_r
        q.y = w2 * h2;                         // pa
        q.z = r2;                              // r2
        q.w = atanf(r2);                       // at2
        precomp[i] = q;
    }
    if (i < BSZ * NMAXG) {
        float4 g = ((const float4*)gt_bboxes)[i];
        float w1 = g.z - g.x, h1 = g.w - g.y + 1e-7f;
        float r1 = w1 / h1;
        float4 q;
        q.x = fminf(w1, h1) / fmaxf(w1, h1);   // gt_r
        q.y = w1 * h1;                         // ga
        q.z = r1;                              // r1
        q.w = atanf(r1);                       // at1
        rowpre[i] = q;
    }
}

// ---- K1: one block per (b,n): cost maxes (full row), compact in-gt list, metric, exact top-13 ----
__global__ __launch_bounds__(256) void k_rows(
    const float* __restrict__ pd_scores, const float* __restrict__ pd_bboxes,
    const float* __restrict__ anc, const int* __restrict__ gt_labels,
    const float* __restrict__ gt_bboxes, const float* __restrict__ mask_gt,
    const float4* __restrict__ precomp, const float4* __restrict__ rowpre,
    unsigned int* __restrict__ fg, unsigned int* __restrict__ firstn,
    float* __restrict__ rowmax)
{
    __shared__ int cidx[CAP];
    __shared__ unsigned long long keys[CAP];
    __shared__ float red[3][4];
    __shared__ unsigned long long bred[4];
    __shared__ int s_cnt, s_pos;

    int row = blockIdx.x;            // b*NMAXG + n
    int b = row >> 6, n = row & 63;
    int t = threadIdx.x;
    int wave = t >> 6, lane = t & 63;
    if (t == 0) { s_cnt = 0; s_pos = 0; }
    __syncthreads();

    float4 g  = ((const float4*)gt_bboxes)[row];
    float4 rp = rowpre[row];                      // gt_r, ga, r1, at1
    const float4* pc = precomp + (size_t)b * NAA;
    const float2* ap2 = (const float2*)anc;

    // phase A: full-row maxes of the 3 cost components + compact in-gt anchor list
    float ms = -1e30f, ma = -1e30f, mw = -1e30f;
    for (int a = t; a < NAA; a += 256) {
        float4 q = pc[a];                         // pd_r, pa, r2, at2
        float cs = 1.0f - fabsf(rp.x - q.x) / fmaxf(rp.x, q.x);
        float ca = 1.0f - fabsf(rp.y - q.y) / fmaxf(rp.y, q.y);
        float cw = fminf(rp.z, q.z) / fmaxf(rp.z, q.z);
        ms = fmaxf(ms, cs); ma = fmaxf(ma, ca); mw = fmaxf(mw, cw);
        float2 apv = ap2[a];
        float d = fminf(fminf(apv.x - g.x, apv.y - g.y), fminf(g.z - apv.x, g.w - apv.y));
        if (d > 1e-9f) {
            int p = atomicAdd(&s_cnt, 1);
            if (p < CAP) cidx[p] = a;
        }
    }
    for (int o = 32; o; o >>= 1) {
        ms = fmaxf(ms, __shfl_xor(ms, o));
        ma = fmaxf(ma, __shfl_xor(ma, o));
        mw = fmaxf(mw, __shfl_xor(mw, o));
    }
    if (lane == 0) { red[0][wave] = ms; red[1][wave] = ma; red[2][wave] = mw; }
    __syncthreads();
    ms = fmaxf(fmaxf(red[0][0], red[0][1]), fmaxf(red[0][2], red[0][3]));
    ma = fmaxf(fmaxf(red[1][0], red[1][1]), fmaxf(red[1][2], red[1][3]));
    mw = fmaxf(fmaxf(red[2][0], red[2][1]), fmaxf(red[2][2], red[2][3]));
    if (t == 0) { rowmax[row * 3 + 0] = ms; rowmax[row * 3 + 1] = ma; rowmax[row * 3 + 2] = mw; }
    float dms = ms + 1e-7f, dma = ma + 1e-7f, dmw = mw + 1e-7f;
    int cnt = s_cnt; cnt = cnt < CAP ? cnt : CAP;

    if (mask_gt[row] <= 0.0f) return;   // block-uniform: masked row selects nothing

    // phase B: full align metric at compact anchors only
    int lbl = gt_labels[row];
    const float* sc = pd_scores + (size_t)b * NAA * NCC + lbl;
    const float4* pb = (const float4*)pd_bboxes + (size_t)b * NAA;
    for (int j = t; j < cnt; j += 256) {
        int a = cidx[j];
        float4 p = pb[a];
        float4 q = pc[a];
        float cs = 1.0f - fabsf(rp.x - q.x) / fmaxf(rp.x, q.x);
        float ca = 1.0f - fabsf(rp.y - q.y) / fmaxf(rp.y, q.y);
        float cw = fminf(rp.z, q.z) / fmaxf(rp.z, q.z);
        float cost = ((cs / dms + cw / dmw) + ca / dma) / 3.0f;
        cost = fmaxf(cost, 0.0f);
        float ov = ciou_pre(g.x, g.y, g.z, g.w, p.x, p.y, p.z, p.w,
                            rp.y, q.y, q.w - rp.w);
        float s = sc[(size_t)a * NCC];
        float o2 = ov * ov; float o3 = o2 * ov; float ov6 = o3 * o3;
        float align = (s * ov6) * cost;
        keys[j] = ((unsigned long long)__float_as_uint(align) << 32)
                | (unsigned long long)(0xFFFFFFFFu - (unsigned)a);
        if (align > 0.0f) atomicAdd(&s_pos, 1);
    }
    __syncthreads();
    int mpos = s_pos;

    // phase C: exact lax.top_k(13) semantics
    if (mpos >= KTOP) {
        // >=13 positive candidates: 13 argmax rounds (value desc, index asc) — all winners positive
        for (int k = 0; k < KTOP; k++) {
            unsigned long long best = 0ull;
            for (int j = t; j < cnt; j += 256) {
                unsigned long long kk = keys[j];
                best = kk > best ? kk : best;
            }
            for (int o = 32; o; o >>= 1) {
                unsigned long long ot = __shfl_xor(best, o);
                best = ot > best ? ot : best;
            }
            if (lane == 0) bred[wave] = best;
            __syncthreads();
            unsigned long long b0 = bred[0], b1 = bred[1], b2 = bred[2], b3 = bred[3];
            unsigned long long m01 = b0 > b1 ? b0 : b1;
            unsigned long long m23 = b2 > b3 ? b2 : b3;
            best = m01 > m23 ? m01 : m23;
            for (int j = t; j < cnt; j += 256)
                if (keys[j] == best) keys[j] = 0ull;   // pop (keys unique: index embedded)
            if (t == 0) {
                int a = (int)(0xFFFFFFFFu - (unsigned)(best & 0xFFFFFFFFull));
                atomicAdd(&fg[b * NAA + a], 1u);
                atomicMin(&firstn[b * NAA + a], (unsigned)n);
            }
            __syncthreads();
        }
    } else {
        // <13 positives: ALL positives selected; remaining Z slots go to the lowest-index
        // zero-valued anchors of the whole row. Only in-gt zeros survive the later
        // in_gts mask; zero anchor a is picked iff (a - #positives_with_idx<a) < Z.
        int Z = KTOP - mpos;
        for (int j = t; j < cnt; j += 256) {
            unsigned long long kk = keys[j];
            int a = (int)(0xFFFFFFFFu - (unsigned)(kk & 0xFFFFFFFFull));
            bool sel;
            if ((kk >> 32) != 0ull) {
                sel = true;
            } else {
                int pcb = 0;
                for (int j2 = 0; j2 < cnt; j2++) {
                    unsigned long long k2 = keys[j2];
                    if ((k2 >> 32) != 0ull) {
                        int a2 = (int)(0xFFFFFFFFu - (unsigned)(k2 & 0xFFFFFFFFull));
                        if (a2 < a) pcb++;
                    }
                }
                sel = (a - pcb) < Z;
            }
            if (sel) {
                atomicAdd(&fg[b * NAA + a], 1u);
                atomicMin(&firstn[b * NAA + a], (unsigned)n);
            }
        }
    }
}

// ---- K2: per anchor: resolve multi-claim via overlap argmax, recompute align, row pos-maxes ----
__global__ __launch_bounds__(256) void k_resolve(
    const float* __restrict__ pd_scores, const float* __restrict__ pd_bboxes,
    const int* __restrict__ gt_labels, const float* __restrict__ gt_bboxes,
    const float4* __restrict__ precomp, const float4* __restrict__ rowpre,
    const unsigned int* __restrict__ fg, const unsigned int* __restrict__ firstn,
    const float* __restrict__ rowmax,
    int* __restrict__ finaln, float* __restrict__ finalalign,
    unsigned int* __restrict__ pos_align, unsigned int* __restrict__ pos_ov)
{
    int i = blockIdx.x * 256 + threadIdx.x;   // b*NAA + a
    if (i >= BSZ * NAA) return;
    int b = i / NAA;
    unsigned int c = fg[i];
    if (c == 0u) { finaln[i] = -1; finalalign[i] = 0.0f; return; }

    const float4 p = ((const float4*)pd_bboxes)[i];
    const float4 q = precomp[i];               // pd_r, pa, r2, at2
    int nstar; float ovstar;
    if (c == 1u) {
        nstar = (int)firstn[i];
        const float4 g  = ((const float4*)gt_bboxes)[b * NMAXG + nstar];
        const float4 rp = rowpre[b * NMAXG + nstar];
        ovstar = ciou_pre(g.x, g.y, g.z, g.w, p.x, p.y, p.z, p.w, rp.y, q.y, q.w - rp.w);
    } else {
        float bestv = -1.0f; nstar = 0; ovstar = 0.0f;
        for (int nn = 0; nn < NMAXG; nn++) {
            const float4 g  = ((const float4*)gt_bboxes)[b * NMAXG + nn];
            const float4 rp = rowpre[b * NMAXG + nn];
            float ov = ciou_pre(g.x, g.y, g.z, g.w, p.x, p.y, p.z, p.w, rp.y, q.y, q.w - rp.w);
            if (ov > bestv) { bestv = ov; nstar = nn; ovstar = ov; }
        }
    }
    const float4 rp = rowpre[b * NMAXG + nstar];
    float cs = 1.0f - fabsf(rp.x - q.x) / fmaxf(rp.x, q.x);
    float ca = 1.0f - fabsf(rp.y - q.y) / fmaxf(rp.y, q.y);
    float cw = fminf(rp.z, q.z) / fmaxf(rp.z, q.z);
    const float* rm = rowmax + (b * NMAXG + nstar) * 3;
    float cost = ((cs / (rm[0] + 1e-7f) + cw / (rm[2] + 1e-7f)) + ca / (rm[1] + 1e-7f)) / 3.0f;
    cost = fmaxf(cost, 0.0f);
    int lbl = gt_labels[b * NMAXG + nstar];
    float s = pd_scores[(size_t)i * NCC + lbl];
    float o2 = ovstar * ovstar, o3 = o2 * ovstar, ov6 = o3 * o3;
    float align = (s * ov6) * cost;
    finaln[i] = nstar;
    finalalign[i] = align;
    atomicMax(&pos_align[b * NMAXG + nstar], __float_as_uint(align));   // all >= 0
    atomicMax(&pos_ov[b * NMAXG + nstar], __float_as_uint(ovstar));
}

// ---- K3: write all outputs (labels, bboxes, full score rows incl. zeros, fg_mask) ----
__global__ __launch_bounds__(256) void k_out(
    const int* __restrict__ gt_labels, const float* __restrict__ gt_bboxes,
    const int* __restrict__ finaln, const float* __restrict__ finalalign,
    const unsigned int* __restrict__ pos_align, const unsigned int* __restrict__ pos_ov,
    float* __restrict__ out)
{
    int i = blockIdx.x * 256 + threadIdx.x;   // b*NAA + a
    if (i >= BSZ * NAA) return;
    int b = i / NAA;
    int nf = finaln[i];
    int tgt = (nf >= 0) ? nf : 0;             // argmax of all-zero column = 0
    int lbl = gt_labels[b * NMAXG + tgt];
    float4 g = ((const float4*)gt_bboxes)[b * NMAXG + tgt];

    out[i] = (float)lbl;                                          // target_labels
    ((float4*)(out + (size_t)BSZ * NAA))[i] = g;                  // target_bboxes

    float* srow = out + (size_t)BSZ * NAA * 5 + (size_t)i * NCC;  // target_scores row
    float4 z; z.x = 0.0f; z.y = 0.0f; z.z = 0.0f; z.w = 0.0f;
    #pragma unroll
    for (int c4 = 0; c4 < NCC / 4; c4++) ((float4*)srow)[c4] = z;

    float* ofg = out + (size_t)BSZ * NAA * (5 + NCC);             // fg_mask
    if (nf >= 0) {
        float pa = __uint_as_float(pos_align[b * NMAXG + nf]);
        float po = __uint_as_float(pos_ov[b * NMAXG + nf]);
        srow[lbl] = (finalalign[i] * po) / (pa + 1e-9f);
        ofg[i] = 1.0f;
    } else {
        ofg[i] = 0.0f;
    }
}

extern "C" void kernel_launch(void* const* d_in, const int* in_sizes, int n_in,
                              void* d_out, int out_size, void* d_ws, size_t ws_size,
                              hipStream_t stream)
{
    const float* pd_scores = (const float*)d_in[0];
    const float* pd_bboxes = (const float*)d_in[1];
    const float* anc       = (const float*)d_in[2];
    const int*   gt_labels = (const int*)d_in[3];
    const float* gt_bboxes = (const float*)d_in[4];
    const float* mask_gt   = (const float*)d_in[5];
    float* out = (float*)d_out;

    char* ws = (char*)d_ws;
    const size_t NBA = (size_t)BSZ * NAA * 4;                 // 537600 B per per-anchor u32/f32
    float4*       precomp = (float4*)(ws);                    // 2,150,400 B
    float4*       rowpre  = (float4*)(ws + 2150400);          //    16,384 B
    unsigned int* fg      = (unsigned int*)(ws + 2166784);
    unsigned int* firstn  = (unsigned int*)(ws + 2166784 + NBA);
    int*          finaln  = (int*)(ws + 2166784 + 2 * NBA);
    float*        fnalign = (float*)(ws + 2166784 + 3 * NBA);
    unsigned int* posal   = (unsigned int*)(ws + 2166784 + 4 * NBA);           // 4096 B
    unsigned int* posov   = (unsigned int*)(ws + 2166784 + 4 * NBA + 4096);    // 4096 B
    float*        rowmax  = (float*)(ws + 2166784 + 4 * NBA + 8192);           // 12288 B

    // per-call re-init (harness does not re-poison between replays)
    hipMemsetAsync(fg, 0, NBA, stream);
    hipMemsetAsync(firstn, 0xFF, NBA, stream);                // UINT_MAX for atomicMin
    hipMemsetAsync(posal, 0, 8192, stream);                   // covers posov too

    int grid = (BSZ * NAA + 255) / 256;
    k_pre<<<grid, 256, 0, stream>>>(pd_bboxes, gt_bboxes, precomp, rowpre);
    k_rows<<<BSZ * NMAXG, 256, 0, stream>>>(pd_scores, pd_bboxes, anc, gt_labels,
                                            gt_bboxes, mask_gt, precomp, rowpre,
                                            fg, firstn, rowmax);
    k_resolve<<<grid, 256, 0, stream>>>(pd_scores, pd_bboxes, gt_labels, gt_bboxes,
                                        precomp, rowpre, fg, firstn, rowmax,
                                        finaln, fnalign, posal, posov);
    k_out<<<grid, 256, 0, stream>>>(gt_labels, gt_bboxes, finaln, fnalign, posal, posov, out);
}